// Round 15
// baseline (324.686 us; speedup 1.0000x reference)
//
#include <hip/hip_runtime.h>
#include <hip/hip_bf16.h>

// Problem constants
#define NE 384      // n_embed
#define HD 64       // head dim
#define TT 8        // block (sequence) length
#define NBATCH 32768

typedef __bf16 bf16;
typedef bf16 bf16x8 __attribute__((ext_vector_type(8)));
typedef bf16 bf16x4 __attribute__((ext_vector_type(4)));
typedef float f32x4 __attribute__((ext_vector_type(4)));

// async global->LDS, 16B per lane, dest = wave-uniform LDS base + lane*16
#define GLOAD_LDS16(g, l) __builtin_amdgcn_global_load_lds(                    \
    (const __attribute__((address_space(1))) void*)(g),                        \
    (__attribute__((address_space(3))) void*)(l), 16, 0, 0)

// LDS fence: all prior LDS reads/writes retired before any later LDS op.
// ("memory" clobber orders memory ops; register-only MFMAs may float — fine.)
#define LDS_FENCE() asm volatile("s_waitcnt lgkmcnt(0)" ::: "memory")

// ---------------------------------------------------------------------------
// Kernel 0: convert Wq|Wk|Wv (each [384,64] f32, row-major, y = x@W) into a
// bf16 fragment table in MFMA B-fragment order:
//   wt[((kk*12 + n)*64 + lane)*8 + j] = W_all[kk*32 + (lane>>4)*8 + j][col]
//   col = n*16 + (lane&15)
// ---------------------------------------------------------------------------
__global__ void prep_wt(const float* __restrict__ Wq, const float* __restrict__ Wk,
                        const float* __restrict__ Wv, bf16* __restrict__ wt) {
    int c = blockIdx.x * blockDim.x + threadIdx.x;
    if (c >= 12 * 12 * 64) return;
    int kk   = c / (12 * 64);
    int rem  = c % (12 * 64);
    int n    = rem / 64;
    int lane = rem % 64;
    int col  = n * 16 + (lane & 15);
    const float* src; int cc;
    if (col < 64)       { src = Wq; cc = col; }
    else if (col < 128) { src = Wk; cc = col - 64; }
    else                { src = Wv; cc = col - 128; }
    int k0 = kk * 32 + (lane >> 4) * 8;
    bf16* dst = wt + (size_t)c * 8;
    #pragma unroll
    for (int j = 0; j < 8; ++j)
        dst[j] = (bf16)src[(size_t)(k0 + j) * 64 + cc];
}

// ---------------------------------------------------------------------------
// Kernel 1: fused qkv projection + causal attention.
// r12 diagnosis: latency-bound (all pipes <35%, occupancy 30%). Fix: LDS
// diet -> 5 blocks/CU (20 waves/CU) instead of 3 (12).
//   - per-wave attention scratch 11 KB -> 6.4 KB by OVERLAYING vT/wei onto
//     the q2/k2 region (never live simultaneously; explicit lgkmcnt fences
//     at the overlay boundaries).
//   - block LDS = max(24.6 KB B-double-buffer, 4 x 6.4 KB) = 25.6 KB.
// Grid: 2048 blocks x 256 threads (4 waves, 4 batches/wave).
// ---------------------------------------------------------------------------
template<bool PREP>
__global__ __launch_bounds__(256, 5)
void fused_head(const float* __restrict__ x, const bf16* __restrict__ wt,
                const float* __restrict__ Wq, const float* __restrict__ Wk,
                const float* __restrict__ Wv, float* __restrict__ out) {
    constexpr int STQ = 72;        // q2/k2 row stride (144 B)
    constexpr int STV = 40;        // vT/wei row stride (80 B)
    constexpr int WSZ = 3200;      // per-wave scratch (elems) = 6400 B
    constexpr int BBUF = 12 * 512; // 12 KB per K-step B buffer
    __shared__ __align__(16) bf16 smem[4 * WSZ];  // 25600 B >= 2*BBUF (24576)

    const int tid  = threadIdx.x;
    const int wid  = tid >> 6;
    const int lane = tid & 63;
    const int lr   = lane & 15;
    const int lg   = lane >> 4;

    // per-wave scratch: phase1 = q2/k2 (2304 el); phase2 overlays vT/wei.
    bf16* base = smem + wid * WSZ;
    bf16* q2  = base;               // [16][STQ]
    bf16* k2  = base + 16 * STQ;    // [16][STQ]
    bf16* vT  = base;               // [64][STV] (overlay)
    bf16* wei = base + 64 * STV;    // [16][STV]

    const int wg   = blockIdx.x * 4 + wid;
    const int row0 = wg * 32;

    f32x4 acc[2][12];
    #pragma unroll
    for (int m = 0; m < 2; ++m)
        #pragma unroll
        for (int n = 0; n < 12; ++n) acc[m][n] = f32x4{0.f, 0.f, 0.f, 0.f};

    const float* xb0 = x + (size_t)(row0 + lr) * NE + lg * 8;
    const float* xb1 = xb0 + (size_t)16 * NE;

    f32x4 c0lo = *(const f32x4*)(xb0);
    f32x4 c0hi = *(const f32x4*)(xb0 + 4);
    f32x4 c1lo = *(const f32x4*)(xb1);
    f32x4 c1hi = *(const f32x4*)(xb1 + 4);

    if (PREP) {
        // prologue: stage K-step 0 into buffer 0 (3 fragments per wave)
        #pragma unroll
        for (int i = 0; i < 3; ++i) {
            int n = wid * 3 + i;
            GLOAD_LDS16(wt + ((size_t)(0 * 12 + n) * 64 + lane) * 8,
                        smem + n * 512);
        }
        __syncthreads();

        for (int kk = 0; kk < 12; ++kk) {
            const int cur = kk & 1;
            if (kk < 11) {
                #pragma unroll
                for (int i = 0; i < 3; ++i) {
                    int n = wid * 3 + i;
                    GLOAD_LDS16(wt + ((size_t)((kk + 1) * 12 + n) * 64 + lane) * 8,
                                smem + (cur ^ 1) * BBUF + n * 512);
                }
            }

            bf16x8 a0, a1;
            #pragma unroll
            for (int j = 0; j < 4; ++j) {
                a0[j]     = (bf16)c0lo[j];
                a0[j + 4] = (bf16)c0hi[j];
                a1[j]     = (bf16)c1lo[j];
                a1[j + 4] = (bf16)c1hi[j];
            }

            if (kk < 11) {
                const float* p0 = xb0 + (kk + 1) * 32;
                const float* p1 = xb1 + (kk + 1) * 32;
                c0lo = *(const f32x4*)(p0);
                c0hi = *(const f32x4*)(p0 + 4);
                c1lo = *(const f32x4*)(p1);
                c1hi = *(const f32x4*)(p1 + 4);
            }

            const bf16* bb = smem + cur * BBUF;
            #pragma unroll
            for (int n = 0; n < 12; ++n) {
                bf16x8 b = *(const bf16x8*)(bb + n * 512 + lane * 8);
                acc[0][n] = __builtin_amdgcn_mfma_f32_16x16x32_bf16(a0, b, acc[0][n], 0, 0, 0);
                acc[1][n] = __builtin_amdgcn_mfma_f32_16x16x32_bf16(a1, b, acc[1][n], 0, 0, 0);
            }
            __syncthreads();   // staged tile landed; safe to swap buffers
        }
        // after the final barrier every wave is past its B reads ->
        // the whole smem array is dead; per-wave overlays are safe.
    } else {  // fallback: gather weights fp32 from global (ws too small)
        for (int kk = 0; kk < 12; ++kk) {
            bf16x8 a0, a1;
            #pragma unroll
            for (int j = 0; j < 4; ++j) {
                a0[j]     = (bf16)c0lo[j];
                a0[j + 4] = (bf16)c0hi[j];
                a1[j]     = (bf16)c1lo[j];
                a1[j + 4] = (bf16)c1hi[j];
            }
            if (kk < 11) {
                const float* p0 = xb0 + (kk + 1) * 32;
                const float* p1 = xb1 + (kk + 1) * 32;
                c0lo = *(const f32x4*)(p0);
                c0hi = *(const f32x4*)(p0 + 4);
                c1lo = *(const f32x4*)(p1);
                c1hi = *(const f32x4*)(p1 + 4);
            }
            #pragma unroll
            for (int n = 0; n < 12; ++n) {
                int col = n * 16 + lr;
                const float* ws = (col < 64) ? (Wq + col)
                                 : (col < 128) ? (Wk + (col - 64))
                                               : (Wv + (col - 128));
                bf16x8 b;
                #pragma unroll
                for (int j = 0; j < 8; ++j)
                    b[j] = (bf16)ws[(size_t)(kk * 32 + lg * 8 + j) * 64];
                acc[0][n] = __builtin_amdgcn_mfma_f32_16x16x32_bf16(a0, b, acc[0][n], 0, 0, 0);
                acc[1][n] = __builtin_amdgcn_mfma_f32_16x16x32_bf16(a1, b, acc[1][n], 0, 0, 0);
            }
        }
        __syncthreads();
    }

    // ---- attention per batch-pair (16 rows = 2 batches), overlay scheme ----
    const float qk_scale = 0.051031036307982884f;  // 384^-0.5
    const f32x4 zero4 = {0.f, 0.f, 0.f, 0.f};
    bf16x8 bzero;
    #pragma unroll
    for (int j = 0; j < 8; ++j) bzero[j] = (bf16)0.f;

    #pragma unroll
    for (int p = 0; p < 2; ++p) {
        // previous phase's LDS reads (PV vb / pa) must retire before
        // overwriting the region with q2/k2.
        LDS_FENCE();

        // phase 1: stage q/k, read QK^T fragments
        #pragma unroll
        for (int nt = 0; nt < 4; ++nt) {
            #pragma unroll
            for (int r = 0; r < 4; ++r) {
                q2[(4 * lg + r) * STQ + nt * 16 + lr] = (bf16)acc[p][nt][r];
                k2[(4 * lg + r) * STQ + nt * 16 + lr] = (bf16)acc[p][4 + nt][r];
            }
        }
        bf16x8 qa0 = *(const bf16x8*)(q2 + lr * STQ + 0 * 32 + lg * 8);
        bf16x8 kb0 = *(const bf16x8*)(k2 + lr * STQ + 0 * 32 + lg * 8);
        bf16x8 qa1 = *(const bf16x8*)(q2 + lr * STQ + 1 * 32 + lg * 8);
        bf16x8 kb1 = *(const bf16x8*)(k2 + lr * STQ + 1 * 32 + lg * 8);

        f32x4 w4 = zero4;
        w4 = __builtin_amdgcn_mfma_f32_16x16x32_bf16(qa0, kb0, w4, 0, 0, 0);
        w4 = __builtin_amdgcn_mfma_f32_16x16x32_bf16(qa1, kb1, w4, 0, 0, 0);

        // softmax in registers (results held through the overlay fence)
        const int sb = lr >> 3;
        const int s  = lr & 7;
        float pn[4];
        #pragma unroll
        for (int r = 0; r < 4; ++r) {
            int tp = 4 * lg + r;
            bool valid = ((tp >> 3) == sb) && (s <= (tp & 7));
            float val = valid ? w4[r] * qk_scale : -1e30f;
            float mx = val;
            mx = fmaxf(mx, __shfl_xor(mx, 1));
            mx = fmaxf(mx, __shfl_xor(mx, 2));
            mx = fmaxf(mx, __shfl_xor(mx, 4));
            float e = valid ? __expf(val - mx) : 0.f;
            float sm = e;
            sm += __shfl_xor(sm, 1);
            sm += __shfl_xor(sm, 2);
            sm += __shfl_xor(sm, 4);
            pn[r] = valid ? e / sm : 0.f;
        }

        // phase 2: qa/kb reads retired -> overlay vT/wei onto q2/k2 region
        LDS_FENCE();

        // zero K=32 padding (cols 16..31); region was clobbered by q2/k2
        *(bf16x8*)(vT + lane * STV + 16) = bzero;
        *(bf16x8*)(vT + lane * STV + 24) = bzero;
        if (lane < 16) {
            *(bf16x8*)(wei + lane * STV + 16) = bzero;
            *(bf16x8*)(wei + lane * STV + 24) = bzero;
        }

        #pragma unroll
        for (int nt = 0; nt < 4; ++nt) {
            bf16x4 vv;
            vv[0] = (bf16)acc[p][8 + nt][0];
            vv[1] = (bf16)acc[p][8 + nt][1];
            vv[2] = (bf16)acc[p][8 + nt][2];
            vv[3] = (bf16)acc[p][8 + nt][3];
            *(bf16x4*)(vT + (nt * 16 + lr) * STV + lg * 4) = vv;  // transposed V
        }
        #pragma unroll
        for (int r = 0; r < 4; ++r)
            wei[(4 * lg + r) * STV + lr] = (bf16)pn[r];

        // P @ V with K=32 (upper 16 k-slots zeroed above)
        bf16x8 pa = *(const bf16x8*)(wei + lr * STV + lg * 8);
        const int bb2 = wg * 4 + p * 2;
        #pragma unroll
        for (int nt = 0; nt < 4; ++nt) {
            bf16x8 vb = *(const bf16x8*)(vT + (nt * 16 + lr) * STV + lg * 8);
            f32x4 o = __builtin_amdgcn_mfma_f32_16x16x32_bf16(pa, vb, zero4, 0, 0, 0);
            #pragma unroll
            for (int r = 0; r < 4; ++r) {
                int tp = 4 * lg + r;
                out[((size_t)(bb2 + (tp >> 3)) * TT + (tp & 7)) * HD + nt * 16 + lr] = o[r];
            }
        }
    }
}

// ---------------------------------------------------------------------------
extern "C" void kernel_launch(void* const* d_in, const int* in_sizes, int n_in,
                              void* d_out, int out_size, void* d_ws, size_t ws_size,
                              hipStream_t stream) {
    const float* x  = (const float*)d_in[0];
    const float* Wq = (const float*)d_in[1];
    const float* Wk = (const float*)d_in[2];
    const float* Wv = (const float*)d_in[3];
    float* out = (float*)d_out;

    const size_t wt_bytes = (size_t)12 * 12 * 64 * 8 * sizeof(bf16);  // 147456
    const int grid = NBATCH / 16;   // 2048 blocks, 4 waves x 4 batches each

    if (ws_size >= wt_bytes) {
        bf16* wt = (bf16*)d_ws;
        prep_wt<<<36, 256, 0, stream>>>(Wq, Wk, Wv, wt);
        fused_head<true><<<grid, 256, 0, stream>>>(x, wt, nullptr, nullptr, nullptr, out);
    } else {
        fused_head<false><<<grid, 256, 0, stream>>>(x, nullptr, Wq, Wk, Wv, out);
    }
}

// Round 16
// 125.122 us; speedup vs baseline: 2.5950x; 2.5950x over previous
//
#include <hip/hip_runtime.h>
#include <hip/hip_bf16.h>

// Problem constants
#define NE 384      // n_embed
#define HD 64       // head dim
#define TT 8        // block (sequence) length
#define NBATCH 32768

typedef __bf16 bf16;
typedef bf16 bf16x8 __attribute__((ext_vector_type(8)));
typedef bf16 bf16x4 __attribute__((ext_vector_type(4)));
typedef float f32x4 __attribute__((ext_vector_type(4)));

// async global->LDS, 16B per lane, dest = wave-uniform LDS base + lane*16
#define GLOAD_LDS16(g, l) __builtin_amdgcn_global_load_lds(                    \
    (const __attribute__((address_space(1))) void*)(g),                        \
    (__attribute__((address_space(3))) void*)(l), 16, 0, 0)

// LDS fence: all prior LDS ops retired before any later LDS op.
#define LDS_FENCE() asm volatile("s_waitcnt lgkmcnt(0)" ::: "memory")

// ---------------------------------------------------------------------------
// Kernel 0: convert Wq|Wk|Wv (each [384,64] f32, row-major, y = x@W) into a
// bf16 fragment table in MFMA B-fragment order:
//   wt[((kk*12 + n)*64 + lane)*8 + j] = W_all[kk*32 + (lane>>4)*8 + j][col]
//   col = n*16 + (lane&15)
// ---------------------------------------------------------------------------
__global__ void prep_wt(const float* __restrict__ Wq, const float* __restrict__ Wk,
                        const float* __restrict__ Wv, bf16* __restrict__ wt) {
    int c = blockIdx.x * blockDim.x + threadIdx.x;
    if (c >= 12 * 12 * 64) return;
    int kk   = c / (12 * 64);
    int rem  = c % (12 * 64);
    int n    = rem / 64;
    int lane = rem % 64;
    int col  = n * 16 + (lane & 15);
    const float* src; int cc;
    if (col < 64)       { src = Wq; cc = col; }
    else if (col < 128) { src = Wk; cc = col - 64; }
    else                { src = Wv; cc = col - 128; }
    int k0 = kk * 32 + (lane >> 4) * 8;
    bf16* dst = wt + (size_t)c * 8;
    #pragma unroll
    for (int j = 0; j < 8; ++j)
        dst[j] = (bf16)src[(size_t)(k0 + j) * 64 + cc];
}

// ---------------------------------------------------------------------------
// Kernel 1: fused qkv projection + causal attention.
// r12: latency-bound (all pipes <35%). r15: lb(256,5) spilled (VGPR 48,
// +780 MB scratch traffic). This round: raise occupancy by SHRINKING state —
// each wave owns ONE 16-row M-tile (2 batches): acc[12] = 48 VGPR.
// lb(256,4): cap 128, no spill; LDS 25.6 KB (overlay scheme, validated r15)
// allows up to 6 blocks/CU -> expect 16-20 waves/CU vs r12's 12.
// Grid: 4096 blocks x 256 threads (4 waves).
// ---------------------------------------------------------------------------
template<bool PREP>
__global__ __launch_bounds__(256, 4)
void fused_head(const float* __restrict__ x, const bf16* __restrict__ wt,
                const float* __restrict__ Wq, const float* __restrict__ Wk,
                const float* __restrict__ Wv, float* __restrict__ out) {
    constexpr int STQ = 72;        // q2/k2 row stride (144 B)
    constexpr int STV = 40;        // vT/wei row stride (80 B)
    constexpr int WSZ = 3200;      // per-wave scratch (elems) = 6400 B
    constexpr int BBUF = 12 * 512; // 12 KB per K-step B buffer
    __shared__ __align__(16) bf16 smem[4 * WSZ];  // 25600 B >= 2*BBUF (24576)

    const int tid  = threadIdx.x;
    const int wid  = tid >> 6;
    const int lane = tid & 63;
    const int lr   = lane & 15;
    const int lg   = lane >> 4;

    // per-wave scratch: phase1 = q2/k2 (2304 el); phase2 overlays vT/wei.
    bf16* base = smem + wid * WSZ;
    bf16* q2  = base;               // [16][STQ]
    bf16* k2  = base + 16 * STQ;    // [16][STQ]
    bf16* vT  = base;               // [64][STV] (overlay)
    bf16* wei = base + 64 * STV;    // [16][STV]

    const int wg   = blockIdx.x * 4 + wid;   // 0..16383
    const int row0 = wg * 16;                // one 16-row M-tile (2 batches)

    f32x4 acc[12];
    #pragma unroll
    for (int n = 0; n < 12; ++n) acc[n] = f32x4{0.f, 0.f, 0.f, 0.f};

    const float* xb0 = x + (size_t)(row0 + lr) * NE + lg * 8;

    // A prefetch ring: 2 K-steps in flight (8 VGPR each)
    f32x4 ab[2][2];
    #pragma unroll
    for (int s = 0; s < 2; ++s) {
        ab[s][0] = *(const f32x4*)(xb0 + s * 32);
        ab[s][1] = *(const f32x4*)(xb0 + s * 32 + 4);
    }

    if (PREP) {
        // prologue: stage K-step 0 into buffer 0 (3 fragments per wave)
        #pragma unroll
        for (int i = 0; i < 3; ++i) {
            int n = wid * 3 + i;
            GLOAD_LDS16(wt + ((size_t)(0 * 12 + n) * 64 + lane) * 8,
                        smem + n * 512);
        }
        __syncthreads();

        for (int kk = 0; kk < 12; ++kk) {
            const int cur = kk & 1;
            if (kk < 11) {
                #pragma unroll
                for (int i = 0; i < 3; ++i) {
                    int n = wid * 3 + i;
                    GLOAD_LDS16(wt + ((size_t)((kk + 1) * 12 + n) * 64 + lane) * 8,
                                smem + (cur ^ 1) * BBUF + n * 512);
                }
            }

            bf16x8 a;
            #pragma unroll
            for (int j = 0; j < 4; ++j) {
                a[j]     = (bf16)ab[cur][0][j];
                a[j + 4] = (bf16)ab[cur][1][j];
            }

            if (kk + 2 < 12) {   // refill the slot just consumed (2 ahead)
                ab[cur][0] = *(const f32x4*)(xb0 + (kk + 2) * 32);
                ab[cur][1] = *(const f32x4*)(xb0 + (kk + 2) * 32 + 4);
            }

            const bf16* bb = smem + cur * BBUF;
            #pragma unroll
            for (int n = 0; n < 12; ++n) {
                bf16x8 b = *(const bf16x8*)(bb + n * 512 + lane * 8);
                acc[n] = __builtin_amdgcn_mfma_f32_16x16x32_bf16(a, b, acc[n], 0, 0, 0);
            }
            __syncthreads();   // staged tile landed; safe to swap buffers
        }
        // after the final barrier all B reads are done -> overlays safe.
    } else {  // fallback: gather weights fp32 from global (ws too small)
        for (int kk = 0; kk < 12; ++kk) {
            const int cur = kk & 1;
            bf16x8 a;
            #pragma unroll
            for (int j = 0; j < 4; ++j) {
                a[j]     = (bf16)ab[cur][0][j];
                a[j + 4] = (bf16)ab[cur][1][j];
            }
            if (kk + 2 < 12) {
                ab[cur][0] = *(const f32x4*)(xb0 + (kk + 2) * 32);
                ab[cur][1] = *(const f32x4*)(xb0 + (kk + 2) * 32 + 4);
            }
            #pragma unroll
            for (int n = 0; n < 12; ++n) {
                int col = n * 16 + lr;
                const float* ws = (col < 64) ? (Wq + col)
                                 : (col < 128) ? (Wk + (col - 64))
                                               : (Wv + (col - 128));
                bf16x8 b;
                #pragma unroll
                for (int j = 0; j < 8; ++j)
                    b[j] = (bf16)ws[(size_t)(kk * 32 + lg * 8 + j) * 64];
                acc[n] = __builtin_amdgcn_mfma_f32_16x16x32_bf16(a, b, acc[n], 0, 0, 0);
            }
        }
        __syncthreads();
    }

    // ---- attention for this wave's batch pair (16 rows = 2 batches) --------
    const float qk_scale = 0.051031036307982884f;  // 384^-0.5
    const f32x4 zero4 = {0.f, 0.f, 0.f, 0.f};
    bf16x8 bzero;
    #pragma unroll
    for (int j = 0; j < 8; ++j) bzero[j] = (bf16)0.f;

    // phase 1: stage q/k (acc 0..3 = q tiles, 4..7 = k tiles)
    #pragma unroll
    for (int nt = 0; nt < 4; ++nt) {
        #pragma unroll
        for (int r = 0; r < 4; ++r) {
            q2[(4 * lg + r) * STQ + nt * 16 + lr] = (bf16)acc[nt][r];
            k2[(4 * lg + r) * STQ + nt * 16 + lr] = (bf16)acc[4 + nt][r];
        }
    }
    bf16x8 qa0 = *(const bf16x8*)(q2 + lr * STQ + 0 * 32 + lg * 8);
    bf16x8 kb0 = *(const bf16x8*)(k2 + lr * STQ + 0 * 32 + lg * 8);
    bf16x8 qa1 = *(const bf16x8*)(q2 + lr * STQ + 1 * 32 + lg * 8);
    bf16x8 kb1 = *(const bf16x8*)(k2 + lr * STQ + 1 * 32 + lg * 8);

    f32x4 w4 = zero4;
    w4 = __builtin_amdgcn_mfma_f32_16x16x32_bf16(qa0, kb0, w4, 0, 0, 0);
    w4 = __builtin_amdgcn_mfma_f32_16x16x32_bf16(qa1, kb1, w4, 0, 0, 0);

    // softmax in registers
    const int sb = lr >> 3;
    const int s  = lr & 7;
    float pn[4];
    #pragma unroll
    for (int r = 0; r < 4; ++r) {
        int tp = 4 * lg + r;
        bool valid = ((tp >> 3) == sb) && (s <= (tp & 7));
        float val = valid ? w4[r] * qk_scale : -1e30f;
        float mx = val;
        mx = fmaxf(mx, __shfl_xor(mx, 1));
        mx = fmaxf(mx, __shfl_xor(mx, 2));
        mx = fmaxf(mx, __shfl_xor(mx, 4));
        float e = valid ? __expf(val - mx) : 0.f;
        float sm = e;
        sm += __shfl_xor(sm, 1);
        sm += __shfl_xor(sm, 2);
        sm += __shfl_xor(sm, 4);
        pn[r] = valid ? e / sm : 0.f;
    }

    // phase 2: qa/kb reads retired -> overlay vT/wei onto q2/k2 region
    LDS_FENCE();

    // zero K=32 padding (cols 16..31); region was clobbered by q2/k2
    *(bf16x8*)(vT + lane * STV + 16) = bzero;
    *(bf16x8*)(vT + lane * STV + 24) = bzero;
    if (lane < 16) {
        *(bf16x8*)(wei + lane * STV + 16) = bzero;
        *(bf16x8*)(wei + lane * STV + 24) = bzero;
    }

    #pragma unroll
    for (int nt = 0; nt < 4; ++nt) {
        bf16x4 vv;
        vv[0] = (bf16)acc[8 + nt][0];
        vv[1] = (bf16)acc[8 + nt][1];
        vv[2] = (bf16)acc[8 + nt][2];
        vv[3] = (bf16)acc[8 + nt][3];
        *(bf16x4*)(vT + (nt * 16 + lr) * STV + lg * 4) = vv;  // transposed V
    }
    #pragma unroll
    for (int r = 0; r < 4; ++r)
        wei[(4 * lg + r) * STV + lr] = (bf16)pn[r];

    // P @ V with K=32 (upper 16 k-slots zeroed above)
    bf16x8 pa = *(const bf16x8*)(wei + lr * STV + lg * 8);
    const int bb2 = wg * 2;
    #pragma unroll
    for (int nt = 0; nt < 4; ++nt) {
        bf16x8 vb = *(const bf16x8*)(vT + (nt * 16 + lr) * STV + lg * 8);
        f32x4 o = __builtin_amdgcn_mfma_f32_16x16x32_bf16(pa, vb, zero4, 0, 0, 0);
        #pragma unroll
        for (int r = 0; r < 4; ++r) {
            int tp = 4 * lg + r;
            out[((size_t)(bb2 + (tp >> 3)) * TT + (tp & 7)) * HD + nt * 16 + lr] = o[r];
        }
    }
}

// ---------------------------------------------------------------------------
extern "C" void kernel_launch(void* const* d_in, const int* in_sizes, int n_in,
                              void* d_out, int out_size, void* d_ws, size_t ws_size,
                              hipStream_t stream) {
    const float* x  = (const float*)d_in[0];
    const float* Wq = (const float*)d_in[1];
    const float* Wk = (const float*)d_in[2];
    const float* Wv = (const float*)d_in[3];
    float* out = (float*)d_out;

    const size_t wt_bytes = (size_t)12 * 12 * 64 * 8 * sizeof(bf16);  // 147456
    const int grid = NBATCH / 8;   // 4096 blocks, 4 waves x 2 batches each

    if (ws_size >= wt_bytes) {
        bf16* wt = (bf16*)d_ws;
        prep_wt<<<36, 256, 0, stream>>>(Wq, Wk, Wv, wt);
        fused_head<true><<<grid, 256, 0, stream>>>(x, wt, nullptr, nullptr, nullptr, out);
    } else {
        fused_head<false><<<grid, 256, 0, stream>>>(x, nullptr, Wq, Wk, Wv, out);
    }
}